// Round 9
// baseline (117.109 us; speedup 1.0000x reference)
//
#include <hip/hip_runtime.h>
#include <stdint.h>

// Problem shape (fixed by reference setup_inputs): B=4096, L=2048.
#define LROW 2048
#define THREADS 256
#define NBINS 1024
#define BPT (NBINS / THREADS)   // 4 bins owned per thread (contiguous bin ids)

// Transposed hist layout: bin b -> [(b&3)*256 + (b>>2)] so the scan's
// thread-contiguous bin ownership is lane-stride-1 (round-8: fixed 16-way
// conflicts; kept).
__device__ __forceinline__ int swz(int b) {
    return ((b & (BPT - 1)) << 8) + (b >> 2);
}

// One block per row. Stable argsort of (masked -> +inf) keys; masked elements
// DROPPED (outputs past `valid` are pad). Valid elements bucket-scatter by
// value (monotone floor(t*1024) -> cross-bucket order by construction).
// Round-9 change: NO within-bucket insertion sort (round-8 showed it was the
// latency bottleneck: dependent ds_read chains + wave-max divergence).
// Instead, an elements-parallel RANK pass: each element counts same-bucket
// keys smaller than its composite key (independent, pipelineable LDS reads)
// and writes its index straight to global at bucket_start + rank. Composite
// (sortable_bits<<32)|idx is all-distinct; ties in t break by lower index ==
// stable argsort == reference argmin semantics.
//
// mask (jnp.bool_) is uploaded by the harness as int32.
__global__ __launch_bounds__(THREADS) void time_greedy_rank_kernel(
    const float* __restrict__ time,
    const int* __restrict__ mask,             // int32: nonzero = excluded
    const int* __restrict__ pad_value_p,
    int* __restrict__ pred,                   // [B, L] int32
    int* __restrict__ valid_out)              // [B]    int32
{
    __shared__ uint64_t keys[LROW];      // 16 KB; scatter fills [0, valid)
    __shared__ uint32_t hstart[NBINS];   // 4 KB: exclusive bucket starts (preserved)
    __shared__ uint32_t hpos[NBINS];     // 4 KB: counts -> running pos -> ends
    __shared__ uint32_t wsum[4];

    const int row = blockIdx.x;
    const int tid = threadIdx.x;
    const int lane = tid & 63;
    const int wid = tid >> 6;

    // ---- init hpos (stride-1) ----
#pragma unroll
    for (int e = 0; e < BPT; ++e) hpos[tid + e * THREADS] = 0;
    __syncthreads();

    // ---- vectorized load + histogram of valid elements ----
    const float4* trow4 = (const float4*)(time + (size_t)row * LROW);
    const int4*   mrow4 = (const int4*)(mask + (size_t)row * LROW);

    uint32_t ukey[8];
    int      bkt[8];
    int      mval[8];
#pragma unroll
    for (int c = 0; c < 2; ++c) {
        const int v = tid + c * THREADS;
        const float4 tq = trow4[v];
        const int4   mq = mrow4[v];
        const float tf[4] = {tq.x, tq.y, tq.z, tq.w};
        const int   mf[4] = {mq.x, mq.y, mq.z, mq.w};
#pragma unroll
        for (int j = 0; j < 4; ++j) {
            const int e = c * 4 + j;
            const uint32_t fb = __float_as_uint(tf[j]);
            // order-preserving float->uint transform (general form)
            ukey[e] = fb ^ ((uint32_t)((int32_t)fb >> 31) | 0x80000000u);
            int b = (int)(tf[j] * (float)NBINS);   // monotone value bucketing
            b = (b < 0) ? 0 : ((b > NBINS - 1) ? NBINS - 1 : b);
            bkt[e] = b;
            mval[e] = mf[j];
            if (!mf[j]) atomicAdd(&hpos[swz(b)], 1u);
        }
    }
    __syncthreads();

    // ---- exclusive prefix sum over 1024 bins (thread t owns bins 4t..4t+3) ----
    uint32_t h[BPT];
    uint32_t lsum = 0;
#pragma unroll
    for (int e = 0; e < BPT; ++e) {
        h[e] = hpos[e * THREADS + tid];   // stride-1
        lsum += h[e];
    }
    uint32_t incl = lsum;                 // wave-inclusive scan
#pragma unroll
    for (int off = 1; off < 64; off <<= 1) {
        const uint32_t y = __shfl_up(incl, off, 64);
        if (lane >= off) incl += y;
    }
    if (lane == 63) wsum[wid] = incl;
    __syncthreads();
    uint32_t woff = 0, total = 0;
#pragma unroll
    for (int w = 0; w < 4; ++w) {
        const uint32_t s = wsum[w];
        if (w < wid) woff += s;
        total += s;
    }
    uint32_t run = woff + incl - lsum;    // exclusive prefix for this thread's bins
#pragma unroll
    for (int e = 0; e < BPT; ++e) {
        hstart[e * THREADS + tid] = run;  // preserved exclusive start
        hpos[e * THREADS + tid] = run;    // running position for scatter
        run += h[e];
    }
    __syncthreads();

    // ---- scatter valid elements into their bucket ranges ----
#pragma unroll
    for (int c = 0; c < 2; ++c) {
#pragma unroll
        for (int j = 0; j < 4; ++j) {
            const int e = c * 4 + j;
            if (!mval[e]) {
                const int i = 4 * tid + c * (4 * THREADS) + j;  // element index
                const uint32_t pos = atomicAdd(&hpos[swz(bkt[e])], 1u);
                keys[pos] = ((uint64_t)ukey[e] << 32) | (uint32_t)i;
            }
        }
    }
    __syncthreads();
    // Invariant: bucket b occupies [hstart[swz(b)], hpos[swz(b)]).

    // ---- elements-parallel rank + direct global write ----
    // Independent LDS reads per element (no dependent chain, no in-place sort).
    const int vld = (int)total;
    const int pad = pad_value_p[0];
    int* prow = pred + (size_t)row * LROW;
#pragma unroll
    for (int c = 0; c < 2; ++c) {
#pragma unroll
        for (int j = 0; j < 4; ++j) {
            const int e = c * 4 + j;
            if (!mval[e]) {
                const int i = 4 * tid + c * (4 * THREADS) + j;
                const uint64_t my = ((uint64_t)ukey[e] << 32) | (uint32_t)i;
                const int sb = swz(bkt[e]);
                const uint32_t s = hstart[sb];
                const uint32_t en = hpos[sb];
                uint32_t rank = 0;
                for (uint32_t q = s; q < en; ++q)
                    rank += (keys[q] < my) ? 1u : 0u;   // excludes self (==)
                prow[s + rank] = i;    // scattered 4B store, dense 8KB/row in L2
            }
        }
    }

    // ---- pad tail [vld, LROW) + valid count (coalesced) ----
    for (int i = vld + tid; i < LROW; i += THREADS) prow[i] = pad;
    if (tid == 0) valid_out[row] = vld;
}

extern "C" void kernel_launch(void* const* d_in, const int* in_sizes, int n_in,
                              void* d_out, int out_size, void* d_ws, size_t ws_size,
                              hipStream_t stream) {
    const float* time = (const float*)d_in[0];
    const int* mask = (const int*)d_in[1];
    const int* pad_value = (const int*)d_in[2];

    const int B = in_sizes[0] / LROW;

    // d_out layout: pred [B*L] int32, then valid [B] int32 (tuple concat order)
    int* pred = (int*)d_out;
    int* valid_out = pred + (size_t)B * LROW;

    time_greedy_rank_kernel<<<B, THREADS, 0, stream>>>(time, mask, pad_value,
                                                       pred, valid_out);
}